// Round 1
// baseline (466.993 us; speedup 1.0000x reference)
//
#include <hip/hip_runtime.h>
#include <hip/hip_bf16.h>
#include <stdint.h>

typedef __hip_bfloat16 bf16;
typedef __attribute__((ext_vector_type(4))) float f32x4;
typedef __attribute__((ext_vector_type(8))) short s16x8;
typedef __attribute__((ext_vector_type(4))) short s16x4;

#define DEV static __device__ __forceinline__

DEV short f2bf(float f) {
  bf16 h = __float2bfloat16(f);
  short s;
  __builtin_memcpy(&s, &h, 2);
  return s;
}

// ------------- transpose + f32->bf16 convert: W[K][N] -> Wt[N][K] ----------
__global__ __launch_bounds__(256) void transpose_cvt(
    const float* __restrict__ W, bf16* __restrict__ Wt, int K, int N)
{
  __shared__ float tile[32][33];
  const int n0 = blockIdx.x << 5;
  const int k0 = blockIdx.y << 5;
  const int tx = threadIdx.x & 31, ty = threadIdx.x >> 5;
#pragma unroll
  for (int i = 0; i < 4; ++i)
    tile[ty + i * 8][tx] = W[(size_t)(k0 + ty + i * 8) * N + n0 + tx];
  __syncthreads();
#pragma unroll
  for (int i = 0; i < 4; ++i)
    Wt[(size_t)(n0 + ty + i * 8) * K + k0 + tx] = __float2bfloat16(tile[tx][ty + i * 8]);
}

// ------------- layernorm (f32 in, bf16 out), D = 1024 ---------------------
__global__ __launch_bounds__(256) void ln_bf16(
    const float* __restrict__ x, const float* __restrict__ g,
    const float* __restrict__ be, bf16* __restrict__ out)
{
  const int t = threadIdx.x;
  const size_t row = blockIdx.x;
  const float4 v = ((const float4*)(x + row * 1024))[t];
  float s = v.x + v.y + v.z + v.w;
  float ss = v.x * v.x + v.y * v.y + v.z * v.z + v.w * v.w;
#pragma unroll
  for (int off = 32; off > 0; off >>= 1) {
    s += __shfl_down(s, off);
    ss += __shfl_down(ss, off);
  }
  __shared__ float sh[8];
  const int wave = t >> 6, lane = t & 63;
  if (!lane) { sh[wave] = s; sh[4 + wave] = ss; }
  __syncthreads();
  s = sh[0] + sh[1] + sh[2] + sh[3];
  ss = sh[4] + sh[5] + sh[6] + sh[7];
  const float mean = s * (1.f / 1024.f);
  const float rstd = rsqrtf(ss * (1.f / 1024.f) - mean * mean + 1e-5f);
  const float4 gv = ((const float4*)g)[t];
  const float4 bv = ((const float4*)be)[t];
  s16x4 o;
  o[0] = f2bf((v.x - mean) * rstd * gv.x + bv.x);
  o[1] = f2bf((v.y - mean) * rstd * gv.y + bv.y);
  o[2] = f2bf((v.z - mean) * rstd * gv.z + bv.z);
  o[3] = f2bf((v.w - mean) * rstd * gv.w + bv.w);
  ((s16x4*)(out + row * 1024))[t] = o;
}

// ------------- residual add + layernorm ------------------------------------
__global__ __launch_bounds__(256) void add_ln_bf16(
    const float* __restrict__ a, const float* __restrict__ x,
    const float* __restrict__ g, const float* __restrict__ be,
    bf16* __restrict__ xres, bf16* __restrict__ xnorm)
{
  const int t = threadIdx.x;
  const size_t row = blockIdx.x;
  const float4 av = ((const float4*)(a + row * 1024))[t];
  const float4 xv = ((const float4*)(x + row * 1024))[t];
  float4 v;
  v.x = av.x + xv.x; v.y = av.y + xv.y; v.z = av.z + xv.z; v.w = av.w + xv.w;
  float s = v.x + v.y + v.z + v.w;
  float ss = v.x * v.x + v.y * v.y + v.z * v.z + v.w * v.w;
#pragma unroll
  for (int off = 32; off > 0; off >>= 1) {
    s += __shfl_down(s, off);
    ss += __shfl_down(ss, off);
  }
  __shared__ float sh[8];
  const int wave = t >> 6, lane = t & 63;
  if (!lane) { sh[wave] = s; sh[4 + wave] = ss; }
  __syncthreads();
  s = sh[0] + sh[1] + sh[2] + sh[3];
  ss = sh[4] + sh[5] + sh[6] + sh[7];
  const float mean = s * (1.f / 1024.f);
  const float rstd = rsqrtf(ss * (1.f / 1024.f) - mean * mean + 1e-5f);
  const float4 gv = ((const float4*)g)[t];
  const float4 bv = ((const float4*)be)[t];
  s16x4 r, o;
  r[0] = f2bf(v.x); r[1] = f2bf(v.y); r[2] = f2bf(v.z); r[3] = f2bf(v.w);
  o[0] = f2bf((v.x - mean) * rstd * gv.x + bv.x);
  o[1] = f2bf((v.y - mean) * rstd * gv.y + bv.y);
  o[2] = f2bf((v.z - mean) * rstd * gv.z + bv.z);
  o[3] = f2bf((v.w - mean) * rstd * gv.w + bv.w);
  ((s16x4*)(xres + row * 1024))[t] = r;
  ((s16x4*)(xnorm + row * 1024))[t] = o;
}

// ------------- GEMM: C[M][N] = A[M][K] @ Bt[N][K]^T, bf16 MFMA -------------
// EPI 0: C bf16 plain. EPI 1: bf16 relu(C + bias). EPI 2: f32 C + bias + add.
template <int EPI>
__global__ __launch_bounds__(256) void gemm_bt(
    const bf16* __restrict__ A, const bf16* __restrict__ Bt,
    void* __restrict__ C, const float* __restrict__ bias,
    const bf16* __restrict__ add_bf16, int M, int N, int K)
{
  __shared__ bf16 sA[128 * 32];
  __shared__ bf16 sB[128 * 32];
  const int tid = threadIdx.x;
  const int wave = tid >> 6, lane = tid & 63;
  const int fr = lane & 15, fg = lane >> 4;
  const int wr = wave >> 1, wc = wave & 1;
  const int nbx = N >> 7;
  const int brow = (blockIdx.x / nbx) << 7;
  const int bcol = (blockIdx.x % nbx) << 7;

  f32x4 acc[4][4] = {};

  const int c0 = wave * 64 + lane;   // staging chunk (16B) index, round 0
  const int c1 = c0 + 256;           // round 1
  const size_t ga0 = (size_t)(brow + (c0 >> 2)) * K + (c0 & 3) * 8;
  const size_t ga1 = (size_t)(brow + (c1 >> 2)) * K + (c1 & 3) * 8;
  const size_t gb0 = (size_t)(bcol + (c0 >> 2)) * K + (c0 & 3) * 8;
  const size_t gb1 = (size_t)(bcol + (c1 >> 2)) * K + (c1 & 3) * 8;
  bf16* sA0 = sA + (size_t)(wave * 64) * 8;
  bf16* sA1 = sA0 + 256 * 8;
  bf16* sB0 = sB + (size_t)(wave * 64) * 8;
  bf16* sB1 = sB0 + 256 * 8;

  for (int kt = 0; kt < K; kt += 32) {
    __builtin_amdgcn_global_load_lds(
        (const __attribute__((address_space(1))) uint32_t*)(A + ga0 + kt),
        (__attribute__((address_space(3))) uint32_t*)sA0, 16, 0, 0);
    __builtin_amdgcn_global_load_lds(
        (const __attribute__((address_space(1))) uint32_t*)(A + ga1 + kt),
        (__attribute__((address_space(3))) uint32_t*)sA1, 16, 0, 0);
    __builtin_amdgcn_global_load_lds(
        (const __attribute__((address_space(1))) uint32_t*)(Bt + gb0 + kt),
        (__attribute__((address_space(3))) uint32_t*)sB0, 16, 0, 0);
    __builtin_amdgcn_global_load_lds(
        (const __attribute__((address_space(1))) uint32_t*)(Bt + gb1 + kt),
        (__attribute__((address_space(3))) uint32_t*)sB1, 16, 0, 0);
    __syncthreads();

    s16x8 af[4], bfr[4];
#pragma unroll
    for (int m = 0; m < 4; ++m)
      af[m] = *(const s16x8*)(sA + ((wr * 64 + m * 16 + fr) * 32 + fg * 8));
#pragma unroll
    for (int n = 0; n < 4; ++n)
      bfr[n] = *(const s16x8*)(sB + ((wc * 64 + n * 16 + fr) * 32 + fg * 8));
#pragma unroll
    for (int m = 0; m < 4; ++m)
#pragma unroll
      for (int n = 0; n < 4; ++n)
        acc[m][n] = __builtin_amdgcn_mfma_f32_16x16x32_bf16(af[m], bfr[n], acc[m][n], 0, 0, 0);
    __syncthreads();
  }

  const int crow = brow + wr * 64;
  const int ccol = bcol + wc * 64;
#pragma unroll
  for (int m = 0; m < 4; ++m) {
#pragma unroll
    for (int n = 0; n < 4; ++n) {
      const int col = ccol + n * 16 + fr;
#pragma unroll
      for (int j = 0; j < 4; ++j) {
        const int row = crow + m * 16 + fg * 4 + j;
        float v = acc[m][n][j];
        if (EPI == 0) {
          ((bf16*)C)[(size_t)row * N + col] = __float2bfloat16(v);
        } else if (EPI == 1) {
          v += bias[col];
          v = fmaxf(v, 0.f);
          ((bf16*)C)[(size_t)row * N + col] = __float2bfloat16(v);
        } else {
          float a;
          {
            bf16 hb = add_bf16[(size_t)row * N + col];
            a = __bfloat162float(hb);
          }
          ((float*)C)[(size_t)row * N + col] = v + bias[col] + a;
        }
      }
    }
  }
}

// ------------- flash attention: QKV [4096][3072] bf16 -> Out [4096][1024] f32
// grid (32 q-tiles of 64, 32 bh). 4 waves, each owns 16 q-rows. No barriers.
__global__ __launch_bounds__(256) void attn_fwd(
    const bf16* __restrict__ QKV, float* __restrict__ Out)
{
  const int LDQ = 3072, S = 2048;
  const int qt = blockIdx.x;
  const int bh = blockIdx.y;
  const int b = bh >> 4, h = bh & 15;
  const int tid = threadIdx.x;
  const int wave = tid >> 6, lane = tid & 63;
  const int fr = lane & 15, fg = lane >> 4;

  const short* base = (const short*)QKV + (size_t)b * 2048 * LDQ;
  const short* Qp = base + h * 64;
  const short* Kp = base + 1024 + h * 64;
  const short* Vp = base + 2048 + h * 64;
  const int q0 = qt * 64 + wave * 16;

  const s16x8 qf0 = *(const s16x8*)(Qp + (size_t)(q0 + fr) * LDQ + fg * 8);
  const s16x8 qf1 = *(const s16x8*)(Qp + (size_t)(q0 + fr) * LDQ + 32 + fg * 8);

  __shared__ short P_lds[4][16 * 40];   // per-wave [16 q][40] (ld=40 keeps b128 align)
  short* Pw = P_lds[wave];

  f32x4 acc[4] = {};
  f32x4 mrow = {-1e30f, -1e30f, -1e30f, -1e30f};
  f32x4 lrow = {};

  for (int kt = 0; kt < S; kt += 32) {
    const s16x8 k00 = *(const s16x8*)(Kp + (size_t)(kt + fr) * LDQ + fg * 8);
    const s16x8 k01 = *(const s16x8*)(Kp + (size_t)(kt + fr) * LDQ + 32 + fg * 8);
    const s16x8 k10 = *(const s16x8*)(Kp + (size_t)(kt + 16 + fr) * LDQ + fg * 8);
    const s16x8 k11 = *(const s16x8*)(Kp + (size_t)(kt + 16 + fr) * LDQ + 32 + fg * 8);
    f32x4 e0 = {}, e1 = {};
    e0 = __builtin_amdgcn_mfma_f32_16x16x32_bf16(qf0, k00, e0, 0, 0, 0);
    e0 = __builtin_amdgcn_mfma_f32_16x16x32_bf16(qf1, k01, e0, 0, 0, 0);
    e1 = __builtin_amdgcn_mfma_f32_16x16x32_bf16(qf0, k10, e1, 0, 0, 0);
    e1 = __builtin_amdgcn_mfma_f32_16x16x32_bf16(qf1, k11, e1, 0, 0, 0);

    const float sc = 0.125f;  // 1/sqrt(64)
    f32x4 s0, s1, mx;
#pragma unroll
    for (int j = 0; j < 4; ++j) {
      s0[j] = e0[j] * sc;
      s1[j] = e1[j] * sc;
      mx[j] = fmaxf(s0[j], s1[j]);
    }
#pragma unroll
    for (int d = 1; d < 16; d <<= 1)
#pragma unroll
      for (int j = 0; j < 4; ++j) mx[j] = fmaxf(mx[j], __shfl_xor(mx[j], d));

    f32x4 alpha, p0, p1, rs;
#pragma unroll
    for (int j = 0; j < 4; ++j) {
      const float mn = fmaxf(mrow[j], mx[j]);
      alpha[j] = __expf(mrow[j] - mn);
      p0[j] = __expf(s0[j] - mn);
      p1[j] = __expf(s1[j] - mn);
      rs[j] = p0[j] + p1[j];
      mrow[j] = mn;
    }
#pragma unroll
    for (int d = 1; d < 16; d <<= 1)
#pragma unroll
      for (int j = 0; j < 4; ++j) rs[j] += __shfl_xor(rs[j], d);
#pragma unroll
    for (int j = 0; j < 4; ++j) lrow[j] = alpha[j] * lrow[j] + rs[j];
#pragma unroll
    for (int nn = 0; nn < 4; ++nn)
#pragma unroll
      for (int j = 0; j < 4; ++j) acc[nn][j] *= alpha[j];

    // P transpose through wave-private LDS (in-order DS, no barrier needed)
#pragma unroll
    for (int j = 0; j < 4; ++j) {
      Pw[(fg * 4 + j) * 40 + fr] = f2bf(p0[j]);
      Pw[(fg * 4 + j) * 40 + 16 + fr] = f2bf(p1[j]);
    }
    const s16x8 pf = *(const s16x8*)(Pw + fr * 40 + fg * 8);

#pragma unroll
    for (int nn = 0; nn < 4; ++nn) {
      s16x8 vf;
#pragma unroll
      for (int i = 0; i < 8; ++i)
        vf[i] = Vp[(size_t)(kt + fg * 8 + i) * LDQ + nn * 16 + fr];
      acc[nn] = __builtin_amdgcn_mfma_f32_16x16x32_bf16(pf, vf, acc[nn], 0, 0, 0);
    }
  }

  f32x4 inv;
#pragma unroll
  for (int j = 0; j < 4; ++j) inv[j] = 1.0f / lrow[j];
  float* outp = Out + (size_t)(b * 2048 + q0) * 1024 + h * 64;
#pragma unroll
  for (int nn = 0; nn < 4; ++nn)
#pragma unroll
    for (int j = 0; j < 4; ++j)
      outp[(size_t)(fg * 4 + j) * 1024 + nn * 16 + fr] = acc[nn][j] * inv[j];
}

// ---------------------------------------------------------------------------
extern "C" void kernel_launch(void* const* d_in, const int* in_sizes, int n_in,
                              void* d_out, int out_size, void* d_ws, size_t ws_size,
                              hipStream_t stream)
{
  const float* x   = (const float*)d_in[0];
  const float* Wq  = (const float*)d_in[1];
  const float* Wk  = (const float*)d_in[2];
  const float* Wv  = (const float*)d_in[3];
  const float* W1  = (const float*)d_in[4];
  const float* b1  = (const float*)d_in[5];
  const float* W2  = (const float*)d_in[6];
  const float* b2  = (const float*)d_in[7];
  const float* g1  = (const float*)d_in[8];
  const float* be1 = (const float*)d_in[9];
  const float* g2  = (const float*)d_in[10];
  const float* be2 = (const float*)d_in[11];
  float* out = (float*)d_out;

  const int M = 4096, D = 1024, DF = 4096;

  // workspace layout (lifetime-overlapped), total ~86 MB
  bf16* Wqkv_t = (bf16*)d_ws;                      // [3072][1024]
  bf16* W1t    = Wqkv_t + (size_t)3072 * 1024;     // [4096][1024]
  bf16* W2t    = W1t + (size_t)4096 * 1024;        // [1024][4096]
  bf16* big    = W2t + (size_t)4096 * 1024;        // QKV [4096][3072], later h [4096][4096]
  bf16* QKV    = big;
  bf16* hbuf   = big;
  char* p2     = (char*)(big + (size_t)M * DF);
  bf16* xnorm  = (bf16*)p2;                        // [4096][1024] bf16 (dead after QKV gemm)
  float* attnO = (float*)p2;                       // [4096][1024] f32 (reuses xnorm region)
  char* p3     = p2 + (size_t)M * D * sizeof(float);
  bf16* xres   = (bf16*)p3;                        // [4096][1024] bf16
  bf16* xnorm2 = xres + (size_t)M * D;             // [4096][1024] bf16

  // 1. weight transpose+convert
  transpose_cvt<<<dim3(32, 32), 256, 0, stream>>>(Wq, Wqkv_t, D, D);
  transpose_cvt<<<dim3(32, 32), 256, 0, stream>>>(Wk, Wqkv_t + (size_t)D * D, D, D);
  transpose_cvt<<<dim3(32, 32), 256, 0, stream>>>(Wv, Wqkv_t + (size_t)2 * D * D, D, D);
  transpose_cvt<<<dim3(128, 32), 256, 0, stream>>>(W1, W1t, D, DF);
  transpose_cvt<<<dim3(32, 128), 256, 0, stream>>>(W2, W2t, DF, D);
  // 2. LN1
  ln_bf16<<<M, 256, 0, stream>>>(x, g1, be1, xnorm);
  // 3. fused QKV projection
  gemm_bt<0><<<(M / 128) * (3072 / 128), 256, 0, stream>>>(
      xnorm, Wqkv_t, QKV, nullptr, nullptr, M, 3072, D);
  // 4. attention
  attn_fwd<<<dim3(32, 32), 256, 0, stream>>>(QKV, attnO);
  // 5. residual + LN2
  add_ln_bf16<<<M, 256, 0, stream>>>(attnO, x, g2, be2, xres, xnorm2);
  // 6. FFN1 (bias + relu fused)
  gemm_bt<1><<<(M / 128) * (DF / 128), 256, 0, stream>>>(
      xres, W1t, hbuf, b1, nullptr, M, DF, D);
  // 7. FFN2 (bias + x_norm2 add fused) -> f32 out
  gemm_bt<2><<<(M / 128) * (D / 128), 256, 0, stream>>>(
      hbuf, W2t, out, b2, xnorm2, M, D, DF);
}

// Round 2
// 465.084 us; speedup vs baseline: 1.0041x; 1.0041x over previous
//
#include <hip/hip_runtime.h>
#include <hip/hip_bf16.h>
#include <stdint.h>

typedef __hip_bfloat16 bf16;
typedef __attribute__((ext_vector_type(4))) float f32x4;
typedef __attribute__((ext_vector_type(8))) short s16x8;
typedef __attribute__((ext_vector_type(4))) short s16x4;

#define DEV static __device__ __forceinline__

DEV short f2bf(float f) {
  bf16 h = __float2bfloat16(f);
  short s;
  __builtin_memcpy(&s, &h, 2);
  return s;
}
DEV float bf2f(short s) {
  bf16 h;
  __builtin_memcpy(&h, &s, 2);
  return __bfloat162float(h);
}

// ------------- transpose + f32->bf16 convert: W[K][N] -> Wt[N][K] ----------
__global__ __launch_bounds__(256) void transpose_cvt(
    const float* __restrict__ W, bf16* __restrict__ Wt, int K, int N)
{
  __shared__ float tile[32][33];
  const int n0 = blockIdx.x << 5;
  const int k0 = blockIdx.y << 5;
  const int tx = threadIdx.x & 31, ty = threadIdx.x >> 5;
#pragma unroll
  for (int i = 0; i < 4; ++i)
    tile[ty + i * 8][tx] = W[(size_t)(k0 + ty + i * 8) * N + n0 + tx];
  __syncthreads();
#pragma unroll
  for (int i = 0; i < 4; ++i)
    Wt[(size_t)(n0 + ty + i * 8) * K + k0 + tx] = __float2bfloat16(tile[tx][ty + i * 8]);
}

// ------------- layernorm (f32 in, bf16 out), D = 1024 ---------------------
__global__ __launch_bounds__(256) void ln_bf16(
    const float* __restrict__ x, const float* __restrict__ g,
    const float* __restrict__ be, bf16* __restrict__ out)
{
  const int t = threadIdx.x;
  const size_t row = blockIdx.x;
  const float4 v = ((const float4*)(x + row * 1024))[t];
  float s = v.x + v.y + v.z + v.w;
  float ss = v.x * v.x + v.y * v.y + v.z * v.z + v.w * v.w;
#pragma unroll
  for (int off = 32; off > 0; off >>= 1) {
    s += __shfl_down(s, off);
    ss += __shfl_down(ss, off);
  }
  __shared__ float sh[8];
  const int wave = t >> 6, lane = t & 63;
  if (!lane) { sh[wave] = s; sh[4 + wave] = ss; }
  __syncthreads();
  s = sh[0] + sh[1] + sh[2] + sh[3];
  ss = sh[4] + sh[5] + sh[6] + sh[7];
  const float mean = s * (1.f / 1024.f);
  const float rstd = rsqrtf(ss * (1.f / 1024.f) - mean * mean + 1e-5f);
  const float4 gv = ((const float4*)g)[t];
  const float4 bv = ((const float4*)be)[t];
  s16x4 o;
  o[0] = f2bf((v.x - mean) * rstd * gv.x + bv.x);
  o[1] = f2bf((v.y - mean) * rstd * gv.y + bv.y);
  o[2] = f2bf((v.z - mean) * rstd * gv.z + bv.z);
  o[3] = f2bf((v.w - mean) * rstd * gv.w + bv.w);
  ((s16x4*)(out + row * 1024))[t] = o;
}

// ------------- residual add + layernorm ------------------------------------
__global__ __launch_bounds__(256) void add_ln_bf16(
    const float* __restrict__ a, const float* __restrict__ x,
    const float* __restrict__ g, const float* __restrict__ be,
    bf16* __restrict__ xres, bf16* __restrict__ xnorm)
{
  const int t = threadIdx.x;
  const size_t row = blockIdx.x;
  const float4 av = ((const float4*)(a + row * 1024))[t];
  const float4 xv = ((const float4*)(x + row * 1024))[t];
  float4 v;
  v.x = av.x + xv.x; v.y = av.y + xv.y; v.z = av.z + xv.z; v.w = av.w + xv.w;
  float s = v.x + v.y + v.z + v.w;
  float ss = v.x * v.x + v.y * v.y + v.z * v.z + v.w * v.w;
#pragma unroll
  for (int off = 32; off > 0; off >>= 1) {
    s += __shfl_down(s, off);
    ss += __shfl_down(ss, off);
  }
  __shared__ float sh[8];
  const int wave = t >> 6, lane = t & 63;
  if (!lane) { sh[wave] = s; sh[4 + wave] = ss; }
  __syncthreads();
  s = sh[0] + sh[1] + sh[2] + sh[3];
  ss = sh[4] + sh[5] + sh[6] + sh[7];
  const float mean = s * (1.f / 1024.f);
  const float rstd = rsqrtf(ss * (1.f / 1024.f) - mean * mean + 1e-5f);
  const float4 gv = ((const float4*)g)[t];
  const float4 bv = ((const float4*)be)[t];
  s16x4 r, o;
  r[0] = f2bf(v.x); r[1] = f2bf(v.y); r[2] = f2bf(v.z); r[3] = f2bf(v.w);
  o[0] = f2bf((v.x - mean) * rstd * gv.x + bv.x);
  o[1] = f2bf((v.y - mean) * rstd * gv.y + bv.y);
  o[2] = f2bf((v.z - mean) * rstd * gv.z + bv.z);
  o[3] = f2bf((v.w - mean) * rstd * gv.w + bv.w);
  ((s16x4*)(xres + row * 1024))[t] = r;
  ((s16x4*)(xnorm + row * 1024))[t] = o;
}

// ------------- GEMM: C[M][N] = A[M][K] @ Bt[N][K]^T, bf16 MFMA -------------
// EPI 0: C bf16 plain. EPI 1: bf16 relu(C + bias). EPI 2: f32 C + bias + add.
template <int EPI>
__global__ __launch_bounds__(256) void gemm_bt(
    const bf16* __restrict__ A, const bf16* __restrict__ Bt,
    void* __restrict__ C, const float* __restrict__ bias,
    const bf16* __restrict__ add_bf16, int M, int N, int K)
{
  __shared__ bf16 sA[128 * 32];
  __shared__ bf16 sB[128 * 32];
  const int tid = threadIdx.x;
  const int wave = tid >> 6, lane = tid & 63;
  const int fr = lane & 15, fg = lane >> 4;
  const int wr = wave >> 1, wc = wave & 1;
  const int nbx = N >> 7;
  const int brow = (blockIdx.x / nbx) << 7;
  const int bcol = (blockIdx.x % nbx) << 7;

  f32x4 acc[4][4] = {};

  const int c0 = wave * 64 + lane;   // staging chunk (16B) index, round 0
  const int c1 = c0 + 256;           // round 1
  const size_t ga0 = (size_t)(brow + (c0 >> 2)) * K + (c0 & 3) * 8;
  const size_t ga1 = (size_t)(brow + (c1 >> 2)) * K + (c1 & 3) * 8;
  const size_t gb0 = (size_t)(bcol + (c0 >> 2)) * K + (c0 & 3) * 8;
  const size_t gb1 = (size_t)(bcol + (c1 >> 2)) * K + (c1 & 3) * 8;
  bf16* sA0 = sA + (size_t)(wave * 64) * 8;
  bf16* sA1 = sA0 + 256 * 8;
  bf16* sB0 = sB + (size_t)(wave * 64) * 8;
  bf16* sB1 = sB0 + 256 * 8;

  for (int kt = 0; kt < K; kt += 32) {
    __builtin_amdgcn_global_load_lds(
        (const __attribute__((address_space(1))) uint32_t*)(A + ga0 + kt),
        (__attribute__((address_space(3))) uint32_t*)sA0, 16, 0, 0);
    __builtin_amdgcn_global_load_lds(
        (const __attribute__((address_space(1))) uint32_t*)(A + ga1 + kt),
        (__attribute__((address_space(3))) uint32_t*)sA1, 16, 0, 0);
    __builtin_amdgcn_global_load_lds(
        (const __attribute__((address_space(1))) uint32_t*)(Bt + gb0 + kt),
        (__attribute__((address_space(3))) uint32_t*)sB0, 16, 0, 0);
    __builtin_amdgcn_global_load_lds(
        (const __attribute__((address_space(1))) uint32_t*)(Bt + gb1 + kt),
        (__attribute__((address_space(3))) uint32_t*)sB1, 16, 0, 0);
    __syncthreads();

    s16x8 af[4], bfr[4];
#pragma unroll
    for (int m = 0; m < 4; ++m)
      af[m] = *(const s16x8*)(sA + ((wr * 64 + m * 16 + fr) * 32 + fg * 8));
#pragma unroll
    for (int n = 0; n < 4; ++n)
      bfr[n] = *(const s16x8*)(sB + ((wc * 64 + n * 16 + fr) * 32 + fg * 8));
#pragma unroll
    for (int m = 0; m < 4; ++m)
#pragma unroll
      for (int n = 0; n < 4; ++n)
        acc[m][n] = __builtin_amdgcn_mfma_f32_16x16x32_bf16(af[m], bfr[n], acc[m][n], 0, 0, 0);
    __syncthreads();
  }

  const int crow = brow + wr * 64;
  const int ccol = bcol + wc * 64;
#pragma unroll
  for (int m = 0; m < 4; ++m) {
#pragma unroll
    for (int n = 0; n < 4; ++n) {
      const int col = ccol + n * 16 + fr;
#pragma unroll
      for (int j = 0; j < 4; ++j) {
        const int row = crow + m * 16 + fg * 4 + j;
        float v = acc[m][n][j];
        if (EPI == 0) {
          ((bf16*)C)[(size_t)row * N + col] = __float2bfloat16(v);
        } else if (EPI == 1) {
          v += bias[col];
          v = fmaxf(v, 0.f);
          ((bf16*)C)[(size_t)row * N + col] = __float2bfloat16(v);
        } else {
          float a;
          {
            bf16 hb = add_bf16[(size_t)row * N + col];
            a = __bfloat162float(hb);
          }
          ((float*)C)[(size_t)row * N + col] = v + bias[col] + a;
        }
      }
    }
  }
}

// ------------- flash attention v2 ------------------------------------------
// QK [4096][2048] bf16 (Q cols 0..1023, K cols 1024..2047), Vt [1024][4096] bf16
// (row = h*64+d, col = b*2048+s).  Out [4096][1024] f32.
// grid (32 q-tiles of 64, 32 bh). 4 waves, each owns 16 q-rows. KVBLK=64.
__global__ __launch_bounds__(256) void attn_fwd(
    const bf16* __restrict__ QK, const bf16* __restrict__ Vt,
    float* __restrict__ Out)
{
  const int LDK = 2048;
  const int qt = blockIdx.x;
  const int bh = blockIdx.y;
  const int b = bh >> 4, h = bh & 15;
  const int tid = threadIdx.x;
  const int wave = tid >> 6, lane = tid & 63;
  const int fr = lane & 15, fg = lane >> 4;

  const short* base = (const short*)QK + (size_t)b * 2048 * LDK;
  const short* Qp = base + h * 64;
  const short* Kp = base + 1024 + h * 64;
  const short* Vp = (const short*)Vt + (size_t)h * 64 * 4096 + b * 2048;
  const int q0 = qt * 64 + wave * 16;

  // Q fragment, pre-scaled by 1/sqrt(64) = 0.125 (exact in bf16)
  s16x8 qf0 = *(const s16x8*)(Qp + (size_t)(q0 + fr) * LDK + fg * 8);
  s16x8 qf1 = *(const s16x8*)(Qp + (size_t)(q0 + fr) * LDK + 32 + fg * 8);
#pragma unroll
  for (int i = 0; i < 8; ++i) {
    qf0[i] = f2bf(bf2f(qf0[i]) * 0.125f);
    qf1[i] = f2bf(bf2f(qf1[i]) * 0.125f);
  }

  __shared__ short P_lds[4][16 * 72];   // per-wave [16 q][72] (rows 16B-aligned)
  short* Pw = P_lds[wave];

  f32x4 acc[4] = {};
  f32x4 mrow = {-1e30f, -1e30f, -1e30f, -1e30f};
  f32x4 lrow = {};   // per-lane partial; fr-reduced once at the end

  for (int kt = 0; kt < 2048; kt += 64) {
    // --- QK^T for 64 k-rows: e[t] is a 16x16 tile (q rows x k cols) ---
    f32x4 e[4];
#pragma unroll
    for (int t = 0; t < 4; ++t) {
      const short* krow = Kp + (size_t)(kt + t * 16 + fr) * LDK;
      const s16x8 k0 = *(const s16x8*)(krow + fg * 8);
      const s16x8 k1 = *(const s16x8*)(krow + 32 + fg * 8);
      f32x4 z = {};
      z = __builtin_amdgcn_mfma_f32_16x16x32_bf16(qf0, k0, z, 0, 0, 0);
      z = __builtin_amdgcn_mfma_f32_16x16x32_bf16(qf1, k1, z, 0, 0, 0);
      e[t] = z;
    }

    // --- row max over 64 k-cols ---
    f32x4 mx;
#pragma unroll
    for (int j = 0; j < 4; ++j)
      mx[j] = fmaxf(fmaxf(e[0][j], e[1][j]), fmaxf(e[2][j], e[3][j]));
#pragma unroll
    for (int d = 1; d < 16; d <<= 1)
#pragma unroll
      for (int j = 0; j < 4; ++j) mx[j] = fmaxf(mx[j], __shfl_xor(mx[j], d));

    // --- defer-max: rescale only if any row max grew by > 8 ---
    const float grow = fmaxf(fmaxf(mx[0] - mrow[0], mx[1] - mrow[1]),
                             fmaxf(mx[2] - mrow[2], mx[3] - mrow[3]));
    if (__any(grow > 8.f)) {
#pragma unroll
      for (int j = 0; j < 4; ++j) {
        const float mn = fmaxf(mrow[j], mx[j]);
        const float al = __expf(mrow[j] - mn);
        lrow[j] *= al;
        mrow[j] = mn;
#pragma unroll
        for (int nn = 0; nn < 4; ++nn) acc[nn][j] *= al;
      }
    }

    // --- exp + per-lane partial row-sum ---
    f32x4 p[4];
#pragma unroll
    for (int j = 0; j < 4; ++j) {
#pragma unroll
      for (int t = 0; t < 4; ++t) p[t][j] = __expf(e[t][j] - mrow[j]);
      lrow[j] += (p[0][j] + p[1][j]) + (p[2][j] + p[3][j]);
    }

    // --- P transpose through wave-private LDS (in-order DS, no barrier) ---
#pragma unroll
    for (int t = 0; t < 4; ++t)
#pragma unroll
      for (int j = 0; j < 4; ++j)
        Pw[(fg * 4 + j) * 72 + t * 16 + fr] = f2bf(p[t][j]);
    const s16x8 pf0 = *(const s16x8*)(Pw + fr * 72 + fg * 8);
    const s16x8 pf1 = *(const s16x8*)(Pw + fr * 72 + 32 + fg * 8);

    // --- PV: V rows contiguous thanks to Vt layout ---
#pragma unroll
    for (int nn = 0; nn < 4; ++nn) {
      const short* vrow = Vp + (size_t)(nn * 16 + fr) * 4096 + kt;
      const s16x8 vf0 = *(const s16x8*)(vrow + fg * 8);
      const s16x8 vf1 = *(const s16x8*)(vrow + 32 + fg * 8);
      acc[nn] = __builtin_amdgcn_mfma_f32_16x16x32_bf16(pf0, vf0, acc[nn], 0, 0, 0);
      acc[nn] = __builtin_amdgcn_mfma_f32_16x16x32_bf16(pf1, vf1, acc[nn], 0, 0, 0);
    }
  }

  // --- final fr-reduction of lrow, then normalize + store ---
#pragma unroll
  for (int d = 1; d < 16; d <<= 1)
#pragma unroll
    for (int j = 0; j < 4; ++j) lrow[j] += __shfl_xor(lrow[j], d);
  f32x4 inv;
#pragma unroll
  for (int j = 0; j < 4; ++j) inv[j] = 1.0f / lrow[j];
  float* outp = Out + (size_t)(b * 2048 + q0) * 1024 + h * 64;
#pragma unroll
  for (int nn = 0; nn < 4; ++nn)
#pragma unroll
    for (int j = 0; j < 4; ++j)
      outp[(size_t)(fg * 4 + j) * 1024 + nn * 16 + fr] = acc[nn][j] * inv[j];
}

// ---------------------------------------------------------------------------
extern "C" void kernel_launch(void* const* d_in, const int* in_sizes, int n_in,
                              void* d_out, int out_size, void* d_ws, size_t ws_size,
                              hipStream_t stream)
{
  const float* x   = (const float*)d_in[0];
  const float* Wq  = (const float*)d_in[1];
  const float* Wk  = (const float*)d_in[2];
  const float* Wv  = (const float*)d_in[3];
  const float* W1  = (const float*)d_in[4];
  const float* b1  = (const float*)d_in[5];
  const float* W2  = (const float*)d_in[6];
  const float* b2  = (const float*)d_in[7];
  const float* g1  = (const float*)d_in[8];
  const float* be1 = (const float*)d_in[9];
  const float* g2  = (const float*)d_in[10];
  const float* be2 = (const float*)d_in[11];
  float* out = (float*)d_out;

  const int M = 4096, D = 1024, DF = 4096;

  // workspace layout (lifetime-overlapped), total ~86 MB
  bf16* Wqk_t = (bf16*)d_ws;                        // [2048][1024]
  bf16* Wv_t  = Wqk_t + (size_t)2048 * 1024;        // [1024][1024]
  bf16* W1t   = Wv_t + (size_t)1024 * 1024;         // [4096][1024]
  bf16* W2t   = W1t + (size_t)4096 * 1024;          // [1024][4096]
  bf16* big   = W2t + (size_t)4096 * 1024;          // 16M elems = 32MB
  bf16* QK    = big;                                // [4096][2048] (dead after attn)
  bf16* Vt    = big + (size_t)8 * 1024 * 1024;      // [1024][4096] (dead after attn)
  bf16* hbuf  = big;                                // [4096][4096] (FFN1 out)
  char* p2    = (char*)(big + (size_t)16 * 1024 * 1024);
  bf16* xnorm = (bf16*)p2;                          // [4096][1024] (dead after gemms)
  float* attnO = (float*)p2;                        // [4096][1024] f32 (reuses xnorm)
  char* p3    = p2 + (size_t)M * D * sizeof(float);
  bf16* xres  = (bf16*)p3;                          // [4096][1024]
  bf16* xnorm2 = xres + (size_t)M * D;              // [4096][1024]

  // 1. weight transpose+convert
  transpose_cvt<<<dim3(32, 32), 256, 0, stream>>>(Wq, Wqk_t, D, D);
  transpose_cvt<<<dim3(32, 32), 256, 0, stream>>>(Wk, Wqk_t + (size_t)D * D, D, D);
  transpose_cvt<<<dim3(32, 32), 256, 0, stream>>>(Wv, Wv_t, D, D);
  transpose_cvt<<<dim3(128, 32), 256, 0, stream>>>(W1, W1t, D, DF);
  transpose_cvt<<<dim3(32, 128), 256, 0, stream>>>(W2, W2t, DF, D);
  // 2. LN1
  ln_bf16<<<M, 256, 0, stream>>>(x, g1, be1, xnorm);
  // 3. QK projection (fused Wq|Wk), row-major [4096][2048]
  gemm_bt<0><<<(M / 128) * (2048 / 128), 256, 0, stream>>>(
      xnorm, Wqk_t, QK, nullptr, nullptr, M, 2048, D);
  // 4. V projection directly transposed: Vt[d][s] = sum_k Wv_t[d][k]*xnorm[s][k]
  gemm_bt<0><<<(D / 128) * (M / 128), 256, 0, stream>>>(
      Wv_t, xnorm, Vt, nullptr, nullptr, D, M, D);
  // 5. attention
  attn_fwd<<<dim3(32, 32), 256, 0, stream>>>(QK, Vt, attnO);
  // 6. residual + LN2
  add_ln_bf16<<<M, 256, 0, stream>>>(attnO, x, g2, be2, xres, xnorm2);
  // 7. FFN1 (bias + relu fused)
  gemm_bt<1><<<(M / 128) * (DF / 128), 256, 0, stream>>>(
      xres, W1t, hbuf, b1, nullptr, M, DF, D);
  // 8. FFN2 (bias + x_norm2 add fused) -> f32 out
  gemm_bt<2><<<(M / 128) * (D / 128), 256, 0, stream>>>(
      hbuf, W2t, out, b2, xnorm2, M, D, DF);
}